// Round 10
// baseline (747.725 us; speedup 1.0000x reference)
//
#include <hip/hip_runtime.h>
#include <hip/hip_cooperative_groups.h>
#include <cmath>

namespace cg = cooperative_groups;

#define DEV __device__ __forceinline__

typedef unsigned short u16;
typedef u16 u16x8 __attribute__((ext_vector_type(8)));
typedef u16 u16x4 __attribute__((ext_vector_type(4)));
typedef short bf16x8 __attribute__((ext_vector_type(8)));
typedef float f32x4 __attribute__((ext_vector_type(4)));

constexpr int B_ = 2;
constexpr int S4[4]    = {48, 24, 12, 6};
constexpr int L4[4]    = {2304, 576, 144, 36};
constexpr int LOFF4[4] = {0, 2304, 2880, 3024};
constexpr int LTOT = 3060;
constexpr int TOFF4[4] = {0, 144, 180, 189};
constexpr int NTT = 192;
constexpr int NCH4[4]   = {72, 18, 5, 2};     // ceil(L/32)
constexpr int CHOFF4[4] = {0, 72, 90, 95};
constexpr int NCHL = 97;
constexpr int NCHC = 72;
constexpr int LC = 2304;
constexpr float LOG2E = 1.44269504088896f;

DEV float siluf(float x) { return x / (1.f + __expf(-x)); }
DEV float softplusf(float x) { return fmaxf(x, 0.f) + log1pf(__expf(-fabsf(x))); }
DEV float b2f(u16 x) { union { float f; unsigned u; } v; v.u = ((unsigned)x) << 16; return v.f; }
DEV u16 f2b(float f) {
  union { float f; unsigned u; } v; v.f = f;
  unsigned r = v.u + 0x7fffu + ((v.u >> 16) & 1u);
  return (u16)(r >> 16);
}

// ------------- level front: in-GEMM + conv + silu + dbc + dt (fused) ---------
__global__ __launch_bounds__(256) void k_front_lvl(
    const float* __restrict__ f0, const float* __restrict__ f1,
    const float* __restrict__ f2, const float* __restrict__ f3,
    const float* __restrict__ Win,   // (4,64,256)
    const float* __restrict__ Wconv, // (4,128,4)
    const float* __restrict__ bconv, // (4,128)
    const float* __restrict__ Wx,    // (4,128,36)
    const float* __restrict__ Wdt,   // (4,4,128)
    const float* __restrict__ bdt,   // (4,128)
    u16* __restrict__ u_l, u16* __restrict__ dt_l,
    u16* __restrict__ Bm_l, u16* __restrict__ Cm_l, u16* __restrict__ z_l) {
  __shared__ float s_x[64 * 20];
  __shared__ float s_xs[19 * 128];
  __shared__ float s_u[16 * 132];
  __shared__ float s_dbc[16 * 36];
  int bid = blockIdx.x;              // B*NTT
  int b = bid / NTT, t = bid - b * NTT;
  int lvl = 0;
  while (lvl < 3 && t >= TOFF4[lvl + 1]) ++lvl;
  int tl = t - TOFF4[lvl];
  int L = L4[lvl], loff = LOFF4[lvl];
  int l0 = tl * 16;
  int nl = min(16, L - l0);
  const float* fx = lvl == 0 ? f0 : lvl == 1 ? f1 : lvl == 2 ? f2 : f3;
  int tid = threadIdx.x;

  for (int i = tid; i < 64 * 20; i += 256) {
    int c = i / 20, r = i - c * 20;
    int l = l0 - 3 + r;
    float v = 0.f;
    if (r < 19 && l >= 0 && l < L) v = fx[(size_t)(b * 64 + c) * L + l];
    s_x[i] = v;
  }
  __syncthreads();
  {  // xz GEMM: 19 rows x 256 cols, K=64
    int j = tid;
    float acc[19];
#pragma unroll
    for (int r = 0; r < 19; ++r) acc[r] = 0.f;
    const float* W = Win + lvl * 64 * 256 + j;
    for (int c = 0; c < 64; ++c) {
      float w = W[c * 256];
#pragma unroll
      for (int r = 0; r < 19; ++r) acc[r] = fmaf(w, s_x[c * 20 + r], acc[r]);
    }
    if (j < 128) {
#pragma unroll
      for (int r = 0; r < 19; ++r) s_xs[r * 128 + j] = acc[r];
    } else {
      int d = j - 128;
      int dti = d >> 4, jj = d & 15;
      for (int r = 3; r < 19; ++r) {
        int l = l0 - 3 + r;
        if (l < l0 + nl)
          z_l[((size_t)(b * 8 + dti) * LTOT + loff + l) * 16 + jj] = f2b(acc[r]);
      }
    }
  }
  __syncthreads();
  for (int i = tid; i < 16 * 128; i += 256) {
    int l = i >> 7, d = i & 127;
    if (l < nl) {
      const float* wc = Wconv + (lvl * 128 + d) * 4;
      float a = bconv[lvl * 128 + d];
#pragma unroll
      for (int k = 0; k < 4; ++k) a = fmaf(wc[k], s_xs[(l + k) * 128 + d], a);
      float uu = siluf(a);
      s_u[l * 132 + d] = uu;
      u_l[((size_t)(b * 8 + (d >> 4)) * LTOT + loff + l0 + l) * 16 + (d & 15)] = f2b(uu);
    }
  }
  __syncthreads();
  for (int i = tid; i < 16 * 36; i += 256) {
    int l = i & 15, jj = i >> 4;
    if (l < nl) {
      const float* wx = Wx + lvl * 128 * 36 + jj;
      float a = 0.f;
      for (int d = 0; d < 128; ++d) a = fmaf(s_u[l * 132 + d], wx[d * 36], a);
      s_dbc[l * 36 + jj] = a;
      if (jj >= 4) {
        int q = jj - 4;
        size_t gb = ((size_t)(b * LTOT) + loff + l0 + l) * 16;
        if (q < 16) Bm_l[gb + q] = f2b(a);
        else        Cm_l[gb + (q - 16)] = f2b(a);
      }
    }
  }
  __syncthreads();
  for (int i = tid; i < 16 * 128; i += 256) {
    int l = i >> 7, d = i & 127;
    if (l < nl) {
      float a = bdt[lvl * 128 + d];
#pragma unroll
      for (int r = 0; r < 4; ++r)
        a = fmaf(s_dbc[l * 36 + r], Wdt[(lvl * 4 + r) * 128 + d], a);
      dt_l[((size_t)(b * 8 + (d >> 4)) * LTOT + loff + l0 + l) * 16 + (d & 15)] =
          f2b(softplusf(a));
    }
  }
}

// ---- fused chunked scan (CH=32): passA -> grid.sync -> prefix -> passC ------
// Scan blocks [0, B*NCHT*NB); for MODE 0 extra blocks do the weight prep.
template <int MODE>
__global__ __launch_bounds__(256) void k_scanAC(
    const u16* __restrict__ dtb, const u16* __restrict__ ub,
    const u16* __restrict__ Bmb, const u16* __restrict__ Cmb,
    const u16* __restrict__ zb,
    const float* __restrict__ Alog, const float* __restrict__ Dsk,
    float* __restrict__ hloc, float* __restrict__ Ssum,
    u16* __restrict__ yg,
    const float* __restrict__ projW, const float* __restrict__ crWout,
    const float* __restrict__ cWin, const float* __restrict__ cWx,
    u16* __restrict__ WPB, u16* __restrict__ WtB,
    u16* __restrict__ WinT, float* __restrict__ WxT) {
  constexpr int DI = MODE ? 512 : 128;
  constexpr int NDT = DI / 16;
  constexpr int NB = DI / 64;
  constexpr int NCHT = MODE ? NCHC : NCHL;
  constexpr int LT = MODE ? LC : LTOT;
  constexpr int NSCAN = B_ * NCHT * NB;
  __shared__ __align__(16) u16 smem[7168];
  __shared__ float sm_t[(MODE == 0) ? 64 * 65 : 8];
  u16* s_dt = smem;                 // [4][32*16]
  u16* s_u  = smem + 2048;
  u16* s_B  = smem + 4096;
  u16* s_C  = smem + 4608;
  u16* s_y  = smem + 5120;          // [32][64]
  cg::grid_group gridg = cg::this_grid();

  int bid = blockIdx.x;
  int tid = threadIdx.x;

  if (MODE == 0 && bid >= NSCAN) {
    // ---- weight prep (352 virtual blocks) ----
    int blk = bid - NSCAN;
    if (blk < 128) {
      int i = blk * 256 + tid;   // 32768
      int d = i >> 6, o = i & 63;
      float acc = 0.f;
#pragma unroll 4
      for (int c = 0; c < 256; ++c)
        acc = fmaf(crWout[d * 256 + c], projW[o * 256 + c], acc);
      WPB[o * 512 + d] = f2b(acc);
    } else if (blk < 192) {
      int i = (blk - 128) * 256 + tid;   // 16384
      WtB[i] = f2b(projW[i]);
    } else if (blk < 256) {
      int t = blk - 192;
      int ct = t & 3, nt = t >> 2;
      int c0 = ct * 64, n0 = nt * 64;
      for (int i = tid; i < 4096; i += 256) {
        int cc = i >> 6, nn = i & 63;
        sm_t[cc * 65 + nn] = cWin[(size_t)(c0 + cc) * 1024 + n0 + nn];
      }
      __syncthreads();
      for (int i = tid; i < 4096; i += 256) {
        int nn = i >> 6, cc = i & 63;
        WinT[(size_t)(n0 + nn) * 256 + c0 + cc] = f2b(sm_t[cc * 65 + nn]);
      }
    } else {
      int i = (blk - 256) * 256 + tid;   // 24576
      int d = i & 511, j = i >> 9;
      WxT[j * 512 + d] = cWx[d * 48 + j];
    }
    gridg.sync();
    return;
  }

  int dblk = bid % NB;
  int rem = bid / NB;
  int gc = rem % NCHT;
  int b = rem / NCHT;
  int lvl = 0, ch = gc, Lq = LC, loff = 0;
  if (MODE == 0) {
    while (lvl < 3 && gc >= CHOFF4[lvl + 1]) ++lvl;
    ch = gc - CHOFF4[lvl];
    Lq = L4[lvl];
    loff = LOFF4[lvl];
  }
  int l0 = ch * 32;
  int len = min(32, Lq - l0);
  int labs0 = loff + l0;
  int q = tid & 3;
  int dl = (tid >> 2) & 15;
  int ti_l = tid >> 6;
  int dti = dblk * 4 + ti_l;
  int d = dti * 16 + dl;
  int n0 = q * 4;

  for (int ti = 0; ti < 4; ++ti) {
    size_t g2 = ((size_t)(b * NDT + dblk * 4 + ti) * LT + labs0) * 16;
    const u16x8* pdt = (const u16x8*)(dtb + g2);
    const u16x8* pu  = (const u16x8*)(ub + g2);
    for (int i = tid; i < len * 2; i += 256) {
      *(u16x8*)&s_dt[ti * 512 + i * 8] = pdt[i];
      *(u16x8*)&s_u [ti * 512 + i * 8] = pu[i];
    }
  }
  {
    size_t gB = ((size_t)b * LT + labs0) * 16;
    for (int i = tid; i < len * 2; i += 256) {
      *(u16x8*)&s_B[i * 8] = *(const u16x8*)&Bmb[gB + i * 8];
      *(u16x8*)&s_C[i * 8] = *(const u16x8*)&Cmb[gB + i * 8];
    }
  }
  __syncthreads();

  int ai = (MODE ? d : lvl * 128 + d);
  float4 al = *(const float4*)&Alog[ai * 16 + n0];
  float kA2[4] = {-__expf(al.x) * LOG2E, -__expf(al.y) * LOG2E,
                  -__expf(al.z) * LOG2E, -__expf(al.w) * LOG2E};
  size_t hix = (((size_t)(b * NCHT) + gc) * DI + d) * 16 + n0;
  float h[4] = {0.f, 0.f, 0.f, 0.f};
  float ss = 0.f;

  // ---- pass A: local scan from h=0 ----
  for (int l = 0; l < len; ++l) {
    float dt = b2f(s_dt[ti_l * 512 + l * 16 + dl]);
    float uu = b2f(s_u [ti_l * 512 + l * 16 + dl]);
    float dtu = dt * uu;
    u16x4 Bv = *(const u16x4*)&s_B[l * 16 + n0];
#pragma unroll
    for (int i = 0; i < 4; ++i) {
      float dA = exp2f(kA2[i] * dt);
      h[i] = fmaf(dA, h[i], dtu * b2f(Bv[i]));
    }
    ss += dt;
  }
  {
    f32x4 hv = {h[0], h[1], h[2], h[3]};
    *(f32x4*)&hloc[hix] = hv;
    if (q == 0) Ssum[((size_t)(b * NCHT) + gc) * DI + d] = ss;
  }
  __threadfence();
  gridg.sync();

  // ---- prefix: combine previous chunks of same (b, d) sequence ----
  int chbase = (MODE == 0) ? CHOFF4[lvl] : 0;
  float hp[4] = {0.f, 0.f, 0.f, 0.f};
  for (int c2 = chbase; c2 < gc; ++c2) {
    size_t bb = ((size_t)(b * NCHT) + c2) * DI + d;
    float S = Ssum[bb];
    float4 hl = *(const float4*)&hloc[bb * 16 + n0];
#pragma unroll
    for (int i = 0; i < 4; ++i)
      hp[i] = fmaf(exp2f(kA2[i] * S), hp[i], ((const float*)&hl)[i]);
  }

  // ---- pass C: replay from hp, emit gated y ----
  float dsk = Dsk[ai];
  for (int l = 0; l < len; ++l) {
    float dt = b2f(s_dt[ti_l * 512 + l * 16 + dl]);
    float uu = b2f(s_u [ti_l * 512 + l * 16 + dl]);
    float dtu = dt * uu;
    u16x4 Bv = *(const u16x4*)&s_B[l * 16 + n0];
    u16x4 Cv = *(const u16x4*)&s_C[l * 16 + n0];
    float p = 0.f;
#pragma unroll
    for (int i = 0; i < 4; ++i) {
      float dA = exp2f(kA2[i] * dt);
      hp[i] = fmaf(dA, hp[i], dtu * b2f(Bv[i]));
      p = fmaf(hp[i], b2f(Cv[i]), p);
    }
    p += __shfl_xor(p, 1, 4);
    p += __shfl_xor(p, 2, 4);
    if (q == 0) s_y[l * 64 + ti_l * 16 + dl] = f2b(fmaf(uu, dsk, p));
  }
  __syncthreads();
  for (int ti = 0; ti < 4; ++ti) {
    size_t g2 = ((size_t)(b * NDT + dblk * 4 + ti) * LT + labs0) * 16;
    for (int i = tid; i < len * 2; i += 256) {
      u16x8 zv = *(const u16x8*)&zb[g2 + i * 8];
      u16x8 yv = *(const u16x8*)&s_y[(i >> 1) * 64 + ti * 16 + (i & 1) * 8];
      u16x8 o;
#pragma unroll
      for (int j = 0; j < 8; ++j) {
        float z = b2f(zv[j]);
        float gate = z / (1.f + __expf(-z));
        o[j] = f2b(b2f(yv[j]) * gate);
      }
      *(u16x8*)&yg[g2 + i * 8] = o;
    }
  }
}

// ---- fused: level out-GEMM + residual -> grid.sync -> resize -> xTb bf16 ----
__global__ __launch_bounds__(256) void k_out_resize(
    const u16* __restrict__ yg_l, const float* __restrict__ Wout, // (4,128,64)
    const float* __restrict__ f0, const float* __restrict__ f1,
    const float* __restrict__ f2, const float* __restrict__ f3,
    float* __restrict__ fout, u16* __restrict__ xTb) {
  __shared__ float s_ygT[128 * 20];
  __shared__ float s_o[16 * 64];
  cg::grid_group gridg = cg::this_grid();
  int bid = blockIdx.x;
  int tid = threadIdx.x;
  if (bid < B_ * NTT) {
    int b = bid / NTT, t = bid - b * NTT;
    int lvl = 0;
    while (lvl < 3 && t >= TOFF4[lvl + 1]) ++lvl;
    int tl = t - TOFF4[lvl];
    int L = L4[lvl], loff = LOFF4[lvl];
    int l0 = tl * 16, nl = min(16, L - l0);
    const float* fx = lvl == 0 ? f0 : lvl == 1 ? f1 : lvl == 2 ? f2 : f3;
    for (int i = tid; i < 16 * 128; i += 256) {
      int d = i & 127, l = i >> 7;
      float v = 0.f;
      if (l < nl)
        v = b2f(yg_l[((size_t)(b * 8 + (d >> 4)) * LTOT + loff + l0 + l) * 16 + (d & 15)]);
      s_ygT[d * 20 + l] = v;
    }
    __syncthreads();
    {
      int c = tid & 63, lg = (tid >> 6) * 4;
      float acc[4] = {0.f, 0.f, 0.f, 0.f};
      const float* W = Wout + lvl * 128 * 64 + c;
      for (int dq = 0; dq < 128; ++dq) {
        float w = W[dq * 64];
        float4 yv = *(const float4*)&s_ygT[dq * 20 + lg];
        acc[0] = fmaf(w, yv.x, acc[0]);
        acc[1] = fmaf(w, yv.y, acc[1]);
        acc[2] = fmaf(w, yv.z, acc[2]);
        acc[3] = fmaf(w, yv.w, acc[3]);
      }
#pragma unroll
      for (int a = 0; a < 4; ++a) s_o[(lg + a) * 64 + c] = acc[a];
    }
    __syncthreads();
    for (int i = tid; i < 16 * 64; i += 256) {
      int c = i >> 4, l = i & 15;
      if (l < nl)
        fout[((size_t)(b * 64) + c) * LTOT + loff + l0 + l] =
            s_o[l * 64 + c] + fx[((size_t)(b * 64) + c) * L + l0 + l];
    }
  }
  __threadfence();
  gridg.sync();
  // resize phase, grid-stride over B*2304*256 (ch fastest)
  int total = B_ * 2304 * 256;
  for (int i = bid * 256 + tid; i < total; i += gridDim.x * 256) {
    int ch = i & 255;
    int rem = i >> 8;
    int hw = rem % 2304;
    int b = rem / 2304;
    int oh = hw / 48, ow = hw - oh * 48;
    int lvl = ch >> 6, c = ch & 63;
    int s = S4[lvl];
    const float* base = fout + ((size_t)(b * 64) + c) * LTOT + LOFF4[lvl];
    float scl = (float)(s - 1) * (1.f / 47.f);
    float fy = oh * scl, fxx = ow * scl;
    int y0 = (int)floorf(fy), x0 = (int)floorf(fxx);
    float wy = fy - y0, wx = fxx - x0;
    int y1 = min(y0 + 1, s - 1), x1 = min(x0 + 1, s - 1);
    float v00 = base[y0 * s + x0], v01 = base[y0 * s + x1];
    float v10 = base[y1 * s + x0], v11 = base[y1 * s + x1];
    float top = v00 * (1.f - wx) + v01 * wx;
    float bot = v10 * (1.f - wx) + v11 * wx;
    xTb[i] = f2b(top * (1.f - wy) + bot * wy);
  }
}

// ----------------- cross input GEMM via MFMA: xT @ WinT^T --------------------
// M=4608 (b*l), N=1024 (j), K=256 (c). BM=64 BN=128 BK=64, 4 waves (32x64).
__global__ __launch_bounds__(256) void k_gemm_mfma(
    const u16* __restrict__ xT,   // (4608, 256) bf16
    const u16* __restrict__ WT,   // (1024, 256) bf16
    u16* __restrict__ xs_c, u16* __restrict__ z_c) {
  __shared__ __align__(16) u16 s_a[64 * 72];
  __shared__ __align__(16) u16 s_b[128 * 72];
  int bid = blockIdx.x;            // 72 * 8
  int nj = bid & 7, bm = bid >> 3;
  int tid = threadIdx.x;
  int lane = tid & 63, w = tid >> 6;
  int wm = (w & 1) * 32, wn = (w >> 1) * 64;
  const int m_base = bm * 64;
  const int n_base = nj * 128;

  f32x4 acc[2][4];
#pragma unroll
  for (int mi = 0; mi < 2; ++mi)
#pragma unroll
    for (int ni = 0; ni < 4; ++ni) acc[mi][ni] = {0.f, 0.f, 0.f, 0.f};

  u16x8 ra0, ra1, rb0, rb1, rb2, rb3;
  auto ld = [&](int c0) {
#pragma unroll
    for (int s = 0; s < 2; ++s) {
      int v = s * 256 + tid;
      int row = v >> 3, kc = (v & 7) * 8;
      u16x8 t = *(const u16x8*)&xT[(size_t)(m_base + row) * 256 + c0 + kc];
      if (s == 0) ra0 = t; else ra1 = t;
    }
#pragma unroll
    for (int s = 0; s < 4; ++s) {
      int v = s * 256 + tid;
      int row = v >> 3, kc = (v & 7) * 8;
      u16x8 t = *(const u16x8*)&WT[(size_t)(n_base + row) * 256 + c0 + kc];
      if (s == 0) rb0 = t; else if (s == 1) rb1 = t;
      else if (s == 2) rb2 = t; else rb3 = t;
    }
  };
  auto st = [&]() {
#pragma unroll
    for (int s = 0; s < 2; ++s) {
      int v = s * 256 + tid;
      int row = v >> 3, kc = (v & 7) * 8;
      *(u16x8*)&s_a[row * 72 + kc] = (s == 0) ? ra0 : ra1;
    }
#pragma unroll
    for (int s = 0; s < 4; ++s) {
      int v = s * 256 + tid;
      int row = v >> 3, kc = (v & 7) * 8;
      const u16x8& t = (s == 0) ? rb0 : (s == 1) ? rb1 : (s == 2) ? rb2 : rb3;
      *(u16x8*)&s_b[row * 72 + kc] = t;
    }
  };
  ld(0);
  int mlane = lane & 15, kg = (lane >> 4) * 8;
  for (int kt = 0; kt < 4; ++kt) {
    st();
    __syncthreads();
    if (kt < 3) ld((kt + 1) * 64);
#pragma unroll
    for (int kk = 0; kk < 2; ++kk) {
      int k0 = kk * 32 + kg;
      bf16x8 af[2], bfr[4];
#pragma unroll
      for (int mi = 0; mi < 2; ++mi)
        af[mi] = *(const bf16x8*)&s_a[(wm + mi * 16 + mlane) * 72 + k0];
#pragma unroll
      for (int ni = 0; ni < 4; ++ni)
        bfr[ni] = *(const bf16x8*)&s_b[(wn + ni * 16 + mlane) * 72 + k0];
#pragma unroll
      for (int mi = 0; mi < 2; ++mi)
#pragma unroll
        for (int ni = 0; ni < 4; ++ni)
          acc[mi][ni] = __builtin_amdgcn_mfma_f32_16x16x32_bf16(
              af[mi], bfr[ni], acc[mi][ni], 0, 0, 0);
    }
    __syncthreads();
  }
  int rgrp = (lane >> 4) * 4;
#pragma unroll
  for (int mi = 0; mi < 2; ++mi) {
#pragma unroll
    for (int ni = 0; ni < 4; ++ni) {
      int n = n_base + wn + ni * 16 + mlane;
#pragma unroll
      for (int r = 0; r < 4; ++r) {
        int gm = m_base + wm + mi * 16 + rgrp + r;
        int b = gm >= 2304;
        int l = gm - b * 2304;
        u16 v = f2b(acc[mi][ni][r]);
        if (n < 512) {
          xs_c[((size_t)(b * LC) + l) * 512 + n] = v;
        } else {
          int dz = n - 512;
          z_c[((size_t)(b * 32 + (dz >> 4)) * LC + l) * 16 + (dz & 15)] = v;
        }
      }
    }
  }
}

// -------- cross mid: conv + silu + dbc + dt, 16-l tiles, 1024 threads --------
__global__ __launch_bounds__(1024) void k_mid_cr(
    const u16* __restrict__ xs_c,    // (B,2304,512) bf16
    const float* __restrict__ Wconv, // (512,4)
    const float* __restrict__ bconv,
    const float* __restrict__ WxT,   // (48,512)
    const float* __restrict__ Wdt,   // (16,512)
    const float* __restrict__ bdt, u16* __restrict__ u_c,
    u16* __restrict__ dt_c, u16* __restrict__ Bm_c, u16* __restrict__ Cm_c) {
  __shared__ __align__(16) u16 s_xs[19 * 512];
  __shared__ __align__(16) u16 s_ub[16 * 520];
  __shared__ __align__(16) float s_wx[48 * 132];
  __shared__ float s_dbc[16 * 48];
  int bid = blockIdx.x;  // B*144
  int b = bid / 144, tl = bid - b * 144;
  int l0 = tl * 16;
  int tid = threadIdx.x;
  for (int i = tid; i < 19 * 64; i += 1024) {
    int r = i >> 6, c8 = (i & 63) * 8;
    int l = l0 - 3 + r;
    u16x8 v = {0, 0, 0, 0, 0, 0, 0, 0};
    if (l >= 0)
      v = *(const u16x8*)&xs_c[((size_t)(b * LC) + l) * 512 + c8];
    *(u16x8*)&s_xs[r * 512 + c8] = v;
  }
  __syncthreads();
  for (int i = tid; i < 16 * 512; i += 1024) {
    int l = i >> 9, d = i & 511;
    const float* wc = Wconv + d * 4;
    float a = bconv[d];
#pragma unroll
    for (int k = 0; k < 4; ++k) a = fmaf(wc[k], b2f(s_xs[(l + k) * 512 + d]), a);
    float uu = siluf(a);
    u16 ub = f2b(uu);
    s_ub[l * 520 + d] = ub;
    u_c[((size_t)(b * 32 + (d >> 4)) * LC + l0 + l) * 16 + (d & 15)] = ub;
  }
  int dl = tid & 15, jj = tid >> 4;
  float a8[8] = {0.f, 0.f, 0.f, 0.f, 0.f, 0.f, 0.f, 0.f};
  for (int kt = 0; kt < 4; ++kt) {
    __syncthreads();
    for (int i = tid; i < 1536; i += 1024) {
      int row = i >> 5, c4 = (i & 31) * 4;
      *(float4*)&s_wx[row * 132 + c4] =
          *(const float4*)&WxT[row * 512 + kt * 128 + c4];
    }
    __syncthreads();
    if (tid < 768) {
      const u16* ur = s_ub + dl * 520 + kt * 128;
      const float* wr = s_wx + jj * 132;
#pragma unroll 4
      for (int kb = 0; kb < 16; ++kb) {
        u16x8 uv = *(const u16x8*)&ur[kb * 8];
        float4 w0 = *(const float4*)&wr[kb * 8];
        float4 w1 = *(const float4*)&wr[kb * 8 + 4];
        a8[0] = fmaf(b2f(uv[0]), w0.x, a8[0]);
        a8[1] = fmaf(b2f(uv[1]), w0.y, a8[1]);
        a8[2] = fmaf(b2f(uv[2]), w0.z, a8[2]);
        a8[3] = fmaf(b2f(uv[3]), w0.w, a8[3]);
        a8[4] = fmaf(b2f(uv[4]), w1.x, a8[4]);
        a8[5] = fmaf(b2f(uv[5]), w1.y, a8[5]);
        a8[6] = fmaf(b2f(uv[6]), w1.z, a8[6]);
        a8[7] = fmaf(b2f(uv[7]), w1.w, a8[7]);
      }
    }
  }
  if (tid < 768) {
    float a = ((a8[0] + a8[1]) + (a8[2] + a8[3])) +
              ((a8[4] + a8[5]) + (a8[6] + a8[7]));
    s_dbc[dl * 48 + jj] = a;
    if (jj >= 16) {
      int q = jj - 16;
      size_t gb = ((size_t)(b * LC) + l0 + dl) * 16;
      if (q < 16) Bm_c[gb + q] = f2b(a);
      else        Cm_c[gb + (q - 16)] = f2b(a);
    }
  }
  __syncthreads();
  for (int i = tid; i < 16 * 512; i += 1024) {
    int l = i >> 9, d = i & 511;
    float a = bdt[d];
#pragma unroll
    for (int r = 0; r < 16; ++r)
      a = fmaf(s_dbc[l * 48 + r], Wdt[r * 512 + d], a);
    dt_c[((size_t)(b * 32 + (d >> 4)) * LC + l0 + l) * 16 + (d & 15)] =
        f2b(softplusf(a));
  }
}

// --- final via MFMA: out = relu(BN([x|yg] @ [WtB|WPB]^T + pb)) ---------------
// M=4608(l), N=64(o), K=768. Grid 288 blocks x 1 wave; M-tile 16.
__global__ __launch_bounds__(64) void k_final_mfma(
    const u16* __restrict__ xTb,   // (4608,256) bf16
    const u16* __restrict__ yg_c,  // (B,32,LC,16) bf16
    const u16* __restrict__ WtB,   // (64,256) bf16
    const u16* __restrict__ WPB,   // (64,512) bf16
    const float* __restrict__ pb, const float* __restrict__ bng,
    const float* __restrict__ bnb, const float* __restrict__ bnm,
    const float* __restrict__ bnv, float* __restrict__ out) {
  int bm = blockIdx.x;             // 288
  int b = bm >= 144;
  int m_base = bm * 16;
  int l_base = m_base - b * 2304;
  int lane = threadIdx.x;
  int mrow = lane & 15;
  int kg = (lane >> 4) * 8;
  f32x4 acc[4];
#pragma unroll
  for (int ni = 0; ni < 4; ++ni) acc[ni] = {0.f, 0.f, 0.f, 0.f};
#pragma unroll
  for (int kt = 0; kt < 8; ++kt) {
    int k0 = kt * 32;
    bf16x8 af = *(const bf16x8*)&xTb[(size_t)(m_base + mrow) * 256 + k0 + kg];
#pragma unroll
    for (int ni = 0; ni < 4; ++ni) {
      bf16x8 bw = *(const bf16x8*)&WtB[(ni * 16 + mrow) * 256 + k0 + kg];
      acc[ni] = __builtin_amdgcn_mfma_f32_16x16x32_bf16(af, bw, acc[ni], 0, 0, 0);
    }
  }
#pragma unroll
  for (int kt = 0; kt < 16; ++kt) {
    int kp = kt * 32 + kg;
    int dt = kp >> 4, j0 = kp & 15;
    bf16x8 af = *(const bf16x8*)
        &yg_c[((size_t)(b * 32 + dt) * LC + l_base + mrow) * 16 + j0];
#pragma unroll
    for (int ni = 0; ni < 4; ++ni) {
      bf16x8 bw = *(const bf16x8*)&WPB[(ni * 16 + mrow) * 512 + kt * 32 + kg];
      acc[ni] = __builtin_amdgcn_mfma_f32_16x16x32_bf16(af, bw, acc[ni], 0, 0, 0);
    }
  }
  int rg = (lane >> 4) * 4;
#pragma unroll
  for (int ni = 0; ni < 4; ++ni) {
    int o = ni * 16 + mrow;
    float bias = pb[o], m = bnm[o], g = bng[o], v = bnv[o], bb2 = bnb[o];
    float scl = g * (1.f / sqrtf(v + 1e-5f));
    float4 r;
    r.x = fmaxf((acc[ni][0] + bias - m) * scl + bb2, 0.f);
    r.y = fmaxf((acc[ni][1] + bias - m) * scl + bb2, 0.f);
    r.z = fmaxf((acc[ni][2] + bias - m) * scl + bb2, 0.f);
    r.w = fmaxf((acc[ni][3] + bias - m) * scl + bb2, 0.f);
    *(float4*)&out[((size_t)(b * 64) + o) * LC + l_base + rg] = r;
  }
}

// -----------------------------------------------------------------------------
extern "C" void kernel_launch(void* const* d_in, const int* in_sizes, int n_in,
                              void* d_out, int out_size, void* d_ws,
                              size_t ws_size, hipStream_t stream) {
  (void)in_sizes; (void)n_in; (void)out_size; (void)ws_size;
  const float* f0 = (const float*)d_in[0];
  const float* f1 = (const float*)d_in[1];
  const float* f2 = (const float*)d_in[2];
  const float* f3 = (const float*)d_in[3];
  const float* lWin   = (const float*)d_in[4];
  const float* lWconv = (const float*)d_in[5];
  const float* lbconv = (const float*)d_in[6];
  const float* lWx    = (const float*)d_in[7];
  const float* lWdt   = (const float*)d_in[8];
  const float* lbdt   = (const float*)d_in[9];
  const float* lAlog  = (const float*)d_in[10];
  const float* lD     = (const float*)d_in[11];
  const float* lWout  = (const float*)d_in[12];
  const float* cWin   = (const float*)d_in[13];
  const float* cWconv = (const float*)d_in[14];
  const float* cbconv = (const float*)d_in[15];
  const float* cWx    = (const float*)d_in[16];
  const float* cWdt   = (const float*)d_in[17];
  const float* cbdt   = (const float*)d_in[18];
  const float* cAlog  = (const float*)d_in[19];
  const float* cD     = (const float*)d_in[20];
  const float* cWout  = (const float*)d_in[21];
  const float* projW  = (const float*)d_in[22];
  const float* projb  = (const float*)d_in[23];
  const float* bng    = (const float*)d_in[24];
  const float* bnb    = (const float*)d_in[25];
  const float* bnm    = (const float*)d_in[26];
  const float* bnv    = (const float*)d_in[27];
  float* out = (float*)d_out;

  float* ws = (float*)d_ws;
  size_t off = 0;
  auto allocf = [&](size_t n) { float* p = ws + off; off += (n + 7) & ~(size_t)7; return p; };
  auto allocb = [&](size_t n) { u16* p = (u16*)(ws + off); off += ((n + 1) / 2 + 7) & ~(size_t)7; return p; };

  float* WxT    = allocf(48 * 512);
  float* fout   = allocf((size_t)B_ * 64 * LTOT);
  float* hloc_l = allocf((size_t)B_ * NCHL * 128 * 16);
  float* S_l    = allocf((size_t)B_ * NCHL * 128);
  float* hloc_c = allocf((size_t)B_ * NCHC * 512 * 16);
  float* S_c    = allocf((size_t)B_ * NCHC * 512);

  u16* WPB   = allocb(64 * 512);
  u16* WtB   = allocb(64 * 256);
  u16* WinT  = allocb(1024 * 256);
  u16* xTb   = allocb((size_t)B_ * LC * 256);
  u16* u_l2  = allocb((size_t)B_ * 8 * LTOT * 16);
  u16* dt_l2 = allocb((size_t)B_ * 8 * LTOT * 16);
  u16* z_l2  = allocb((size_t)B_ * 8 * LTOT * 16);
  u16* yg_l2 = allocb((size_t)B_ * 8 * LTOT * 16);
  u16* Bm_l2 = allocb((size_t)B_ * LTOT * 16);
  u16* Cm_l2 = allocb((size_t)B_ * LTOT * 16);
  u16* xs_c2 = allocb((size_t)B_ * LC * 512);
  u16* u_c2  = allocb((size_t)B_ * 32 * LC * 16);
  u16* dt_c2 = allocb((size_t)B_ * 32 * LC * 16);
  u16* z_c2  = allocb((size_t)B_ * 32 * LC * 16);
  u16* yg_c2 = allocb((size_t)B_ * 32 * LC * 16);
  u16* Bm_c2 = allocb((size_t)B_ * LC * 16);
  u16* Cm_c2 = allocb((size_t)B_ * LC * 16);

  k_front_lvl<<<B_ * NTT, 256, 0, stream>>>(f0, f1, f2, f3, lWin, lWconv,
                                            lbconv, lWx, lWdt, lbdt, u_l2,
                                            dt_l2, Bm_l2, Cm_l2, z_l2);

  {  // fused level scan + weight prep (cooperative)
    const u16 *a0 = dt_l2, *a1 = u_l2, *a2 = Bm_l2, *a3 = Cm_l2, *a4 = z_l2;
    const float *a5 = lAlog, *a6 = lD;
    float *a7 = hloc_l, *a8 = S_l;
    u16* a9 = yg_l2;
    const float *p0 = projW, *p1 = cWout, *p2 = cWin, *p3 = cWx;
    u16 *p4 = WPB, *p5 = WtB, *p6 = WinT;
    float* p7 = WxT;
    void* args[] = {&a0, &a1, &a2, &a3, &a4, &a5, &a6, &a7, &a8, &a9,
                    &p0, &p1, &p2, &p3, &p4, &p5, &p6, &p7};
    hipLaunchCooperativeKernel((void*)k_scanAC<0>, dim3(B_ * NCHL * 2 + 352),
                               dim3(256), args, 0, stream);
  }

  {  // fused out-GEMM + resize (cooperative)
    const u16* a0 = yg_l2;
    const float *a1 = lWout, *a2 = f0, *a3 = f1, *a4 = f2, *a5 = f3;
    float* a6 = fout;
    u16* a7 = xTb;
    void* args[] = {&a0, &a1, &a2, &a3, &a4, &a5, &a6, &a7};
    hipLaunchCooperativeKernel((void*)k_out_resize, dim3(512), dim3(256), args,
                               0, stream);
  }

  k_gemm_mfma<<<72 * 8, 256, 0, stream>>>(xTb, WinT, xs_c2, z_c2);
  k_mid_cr<<<B_ * 144, 1024, 0, stream>>>(xs_c2, cWconv, cbconv, WxT, cWdt,
                                          cbdt, u_c2, dt_c2, Bm_c2, Cm_c2);

  {  // fused cross scan (cooperative)
    const u16 *a0 = dt_c2, *a1 = u_c2, *a2 = Bm_c2, *a3 = Cm_c2, *a4 = z_c2;
    const float *a5 = cAlog, *a6 = cD;
    float *a7 = hloc_c, *a8 = S_c;
    u16* a9 = yg_c2;
    const float *p0 = nullptr, *p1 = nullptr, *p2 = nullptr, *p3 = nullptr;
    u16 *p4 = nullptr, *p5 = nullptr, *p6 = nullptr;
    float* p7 = nullptr;
    void* args[] = {&a0, &a1, &a2, &a3, &a4, &a5, &a6, &a7, &a8, &a9,
                    &p0, &p1, &p2, &p3, &p4, &p5, &p6, &p7};
    hipLaunchCooperativeKernel((void*)k_scanAC<1>, dim3(B_ * NCHC * 8),
                               dim3(256), args, 0, stream);
  }

  k_final_mfma<<<288, 64, 0, stream>>>(xTb, yg_c2, WtB, WPB, projb, bng, bnb,
                                       bnm, bnv, out);
}